// Round 7
// baseline (225.007 us; speedup 1.0000x reference)
//
#include <hip/hip_runtime.h>
#include <hip/hip_bf16.h>

#define NN 8192
#define NB 8192                               // value buckets over [0,1)
#define EPSF 1e-8f
#define LOG2E 1.4426950408889634f
#define LN2f 0.6931471805599453f
#define CHUNKS 4
#define CH (NN / CHUNKS)                      // 2048 j-elements per chunk
#define KMAX (CH / 64)                        // 32 k-iters (64 elems each)
#define RG (NN / 16)                          // 512 row-groups
#define NBLK (RG * CHUNKS)                    // 2048 blocks in dispatch B
#define A2SCALE (20.0f * LOG2E)               // (pred/0.05)*log2(e)

__device__ __forceinline__ int bucket_of(float y) {
    return min(max((int)(y * 8192.0f), 0), NB - 1);
}

// ---------------------------------------------------------------------------
// Dispatch A: fused counting sort, 32 blocks x 256 threads.
// Grid barrier via flag array: d_ws is 0xAA-poisoned before every launch
// (harness guarantee), so flags start NEGATIVE as int -> gens 1,2,3 work
// with no separate init dispatch. 32 blocks << 256 CUs: always co-resident.
// ---------------------------------------------------------------------------
__device__ __forceinline__ void barrier32(int* sflag, int b, int t, int gen) {
    __syncthreads();                          // drain this block's stores (vmcnt 0)
    if (t == 0) {
        __threadfence();
        __hip_atomic_store(&sflag[b], gen, __ATOMIC_RELEASE, __HIP_MEMORY_SCOPE_AGENT);
    }
    if (t < 32) {
        while (__hip_atomic_load(&sflag[t], __ATOMIC_ACQUIRE, __HIP_MEMORY_SCOPE_AGENT) < gen) {}
    }
    __syncthreads();
}

__global__ __launch_bounds__(256) void sort32(const float* __restrict__ yt,
                                              const float* __restrict__ pred,
                                              float* __restrict__ ybkt,
                                              float* __restrict__ a2bkt,
                                              int* __restrict__ offs,
                                              int* __restrict__ hist,
                                              int* __restrict__ cursor,
                                              int* __restrict__ sflag) {
    __shared__ int wred4[4];
    const int t = threadIdx.x, b = blockIdx.x;
    const int lane = t & 63, wave = t >> 6;
    const int gid = b * 256 + t;              // 32*256 == 8192 == NN

    // P0: zero hist
    hist[gid] = 0;
    barrier32(sflag, b, t, 1);

    // P1: histogram (global atomics, ~uniform buckets -> low contention)
    const float y = yt[gid];
    const int bk = bucket_of(y);
    atomicAdd(&hist[bk], 1);
    barrier32(sflag, b, t, 2);

    // P2: exclusive scan (block 0 only; GLC loads so L1 can't serve stale zeros)
    if (b == 0) {
        const int base = t * 32;
        int loc[32]; int sum = 0;
#pragma unroll
        for (int k = 0; k < 32; ++k) {
            loc[k] = __hip_atomic_load(&hist[base + k], __ATOMIC_RELAXED, __HIP_MEMORY_SCOPE_AGENT);
            sum += loc[k];
        }
        int incl = sum;
        for (int d = 1; d < 64; d <<= 1) {
            int n = __shfl_up(incl, d);
            if (lane >= d) incl += n;
        }
        if (lane == 63) wred4[wave] = incl;
        __syncthreads();
        int wpre = 0;
        for (int w2 = 0; w2 < 4; ++w2) wpre += (w2 < wave) ? wred4[w2] : 0;
        int run = wpre + incl - sum;          // exclusive base of this thread's buckets
#pragma unroll
        for (int k = 0; k < 32; ++k) {
            offs[base + k] = run;
            cursor[base + k] = run;
            run += loc[k];
        }
        if (t == 255) offs[NB] = run;         // == NN
    }
    barrier32(sflag, b, t, 3);

    // P3: scatter (within-bucket order arbitrary: loss is permutation-invariant)
    const int pos = atomicAdd(&cursor[bk], 1);
    ybkt[pos] = y;
    a2bkt[pos] = pred[gid] * A2SCALE;
}

// ---------------------------------------------------------------------------
// Dispatch B: register-staged sorted-prefix two-pass + embedded finalize.
// Block (rg,c): 16 sorted rows x chunk c (2048 j's). Each wave holds its
// chunk's (a_j, a_j*y_j) in 64 VGPRs -> no LDS, no syncthreads in hot path.
//   unmasked k (all 64 j's bucket <= b0-2): L = fma(a,x,-c); max / exp2-sum
//   straddle k: exact fsub(x,y) > EPS mask (y reloaded from L2, few iters)
// Block 7 == (rg=511, c=3) under the swizzle: longest work; after its own
// partials it spins on all 2048 done-flags and runs the finalize inline.
// ---------------------------------------------------------------------------
__global__ __launch_bounds__(256, 4) void pro_fused(const float* __restrict__ ybkt,
                                                    const float* __restrict__ a2bkt,
                                                    const int* __restrict__ offs,
                                                    float2* __restrict__ partial,
                                                    int* __restrict__ pflag,
                                                    float* __restrict__ out) {
    __shared__ float fredm[4];
    __shared__ float2 fred2[4];

    const int t = threadIdx.x, lane = t & 63, wave = t >> 6;
    const int braw = blockIdx.x;
    const int rgl = braw >> 2, c = braw & 3;
    // load-balance swizzle: pair long (high rg) with short (low rg) in dispatch order
    const int rg = (rgl & 1) ? (RG - 1 - (rgl >> 1)) : (rgl >> 1);
    const int j0 = c * CH;
    const int row0 = rg * 16 + wave * 4;

    // block-level inactive test (end is monotone in sorted position)
    const float x15 = ybkt[rg * 16 + 15];
    const bool active = (offs[bucket_of(x15) + 1] > j0);

    float M[4], s[4];
#pragma unroll
    for (int r = 0; r < 4; ++r) { M[r] = -INFINITY; s[r] = 0.0f; }

    if (active) {
        float x[4];
#pragma unroll
        for (int r = 0; r < 4; ++r) x[r] = ybkt[row0 + r];
        const int b0 = bucket_of(x[0]), b3 = bucket_of(x[3]);
        const int u0 = (b0 > 0) ? offs[b0 - 1] : 0;   // below: valid for all 4 rows
        const int e3 = offs[b3 + 1];                  // at/after: invalid for all
        const int kfull = min(max((u0 - j0) >> 6, 0), KMAX);
        const int kend  = min(max((e3 - j0 + 63) >> 6, kfull), KMAX);

        // register staging: (a, a*y) for this lane's 32 strided j's
        float A[KMAX], C[KMAX];
#pragma unroll
        for (int k = 0; k < KMAX; ++k) {
            if (k < kend) {
                const int j = j0 + lane + (k << 6);
                const float a = a2bkt[j];
                A[k] = a;
                C[k] = a * ybkt[j];
            }
        }

        // ---- pass 1: masked max ----
#pragma unroll
        for (int k = 0; k < KMAX; ++k) {
            if (k < kfull) {
#pragma unroll
                for (int r = 0; r < 4; ++r)
                    M[r] = fmaxf(M[r], __builtin_fmaf(A[k], x[r], -C[k]));
            } else if (k < kend) {
                const float yv = ybkt[j0 + lane + (k << 6)];
#pragma unroll
                for (int r = 0; r < 4; ++r) {
                    const float W = x[r] - yv;
                    const float L = __builtin_fmaf(A[k], x[r], -C[k]);
                    M[r] = fmaxf(M[r], (W > EPSF) ? L : -INFINITY);
                }
            }
        }
#pragma unroll
        for (int r = 0; r < 4; ++r)
            for (int m = 1; m < 64; m <<= 1) M[r] = fmaxf(M[r], __shfl_xor(M[r], m));

        // ---- pass 2: masked exp2 sum ----
#pragma unroll
        for (int k = 0; k < KMAX; ++k) {
            if (k < kfull) {
#pragma unroll
                for (int r = 0; r < 4; ++r)
                    s[r] += exp2f(__builtin_fmaf(A[k], x[r], -C[k]) - M[r]);
            } else if (k < kend) {
                const float yv = ybkt[j0 + lane + (k << 6)];
#pragma unroll
                for (int r = 0; r < 4; ++r) {
                    const float W = x[r] - yv;
                    const float tt = __builtin_fmaf(A[k], x[r], -C[k]) - M[r];
                    s[r] += exp2f((W > EPSF) ? tt : -INFINITY);
                }
            }
        }
#pragma unroll
        for (int r = 0; r < 4; ++r)
            for (int m = 1; m < 64; m <<= 1) s[r] += __shfl_xor(s[r], m);
    }

    if (lane == 0) {
#pragma unroll
        for (int r = 0; r < 4; ++r)
            partial[c * NN + row0 + r] = make_float2(M[r], s[r]);
    }

    // publish done-flag (poison 0xAAAAAAAA is negative as int -> < 1 pre-launch)
    __syncthreads();
    if (t == 0) {
        __threadfence();
        __hip_atomic_store(&pflag[braw], 1, __ATOMIC_RELEASE, __HIP_MEMORY_SCOPE_AGENT);
    }

    // ---- embedded finalize: block 7 (rg=511,c=3 -> longest work) ----
    if (braw == 7) {
        for (int i = t; i < NBLK; i += 256)
            while (__hip_atomic_load(&pflag[i], __ATOMIC_ACQUIRE, __HIP_MEMORY_SCOPE_AGENT) < 1) {}
        __syncthreads();
        __threadfence();

        float mn = INFINITY;
        for (int i = t; i < NN; i += 256) mn = fminf(mn, ybkt[i]);
#pragma unroll
        for (int m = 1; m < 64; m <<= 1) mn = fminf(mn, __shfl_xor(mn, m));
        if (lane == 0) fredm[wave] = mn;
        __syncthreads();
        const float ymin = fminf(fminf(fredm[0], fredm[1]), fminf(fredm[2], fredm[3]));

        float wtot = 0.f, wcnt = 0.f;
        for (int p = t; p < NN; p += 256) {
            const float xv = ybkt[p];
            const float w = xv - ymin;        // == weight_k (max masked gap)
            const float lp = a2bkt[p] * w;    // logit_pos, log2-scaled
            const float2 p0 = partial[0 * NN + p];
            const float2 p1 = partial[1 * NN + p];
            const float2 p2 = partial[2 * NN + p];
            const float2 p3 = partial[3 * NN + p];
            const float Mx = fmaxf(lp, fmaxf(fmaxf(p0.x, p1.x), fmaxf(p2.x, p3.x)));
            float sum = exp2f(lp - Mx);
            sum += p0.y * exp2f(p0.x - Mx);
            sum += p1.y * exp2f(p1.x - Mx);
            sum += p2.y * exp2f(p2.x - Mx);
            sum += p3.y * exp2f(p3.x - Mx);
            const float logp = (lp - Mx) * LN2f - __logf(sum);
            if (w > EPSF) { wtot += logp; wcnt += 1.f; }
        }
#pragma unroll
        for (int m = 1; m < 64; m <<= 1) { wtot += __shfl_xor(wtot, m); wcnt += __shfl_xor(wcnt, m); }
        if (lane == 0) fred2[wave] = make_float2(wtot, wcnt);
        __syncthreads();
        if (t == 0) {
            const float bt = fred2[0].x + fred2[1].x + fred2[2].x + fred2[3].x;
            const float bc = fred2[0].y + fred2[1].y + fred2[2].y + fred2[3].y;
            out[0] = (bc > 0.f) ? (-bt / bc) : 0.f;
        }
    }
}

extern "C" void kernel_launch(void* const* d_in, const int* in_sizes, int n_in,
                              void* d_out, int out_size, void* d_ws, size_t ws_size,
                              hipStream_t stream) {
    const float* pred = (const float*)d_in[0];  // predict_similarity
    const float* yt   = (const float*)d_in[1];  // true_similarity

    float* ybkt   = (float*)d_ws;               // [NN]
    float* a2bkt  = ybkt + NN;                  // [NN]
    int*   offs   = (int*)(a2bkt + NN);         // [NB+1] (+pad)
    int*   hist   = offs + NB + 8;              // [NB]
    int*   cursor = hist + NB;                  // [NB]
    int*   sflag  = cursor + NB;                // [32] (+pad)
    int*   pflag  = sflag + 64;                 // [NBLK]
    float2* partial = (float2*)(pflag + NBLK);  // [CHUNKS][NN] — fully overwritten

    sort32<<<32, 256, 0, stream>>>(yt, pred, ybkt, a2bkt, offs, hist, cursor, sflag);
    pro_fused<<<NBLK, 256, 0, stream>>>(ybkt, a2bkt, offs, partial, pflag, (float*)d_out);
}

// Round 9
// 150.397 us; speedup vs baseline: 1.4961x; 1.4961x over previous
//
#include <hip/hip_runtime.h>
#include <hip/hip_bf16.h>

#define NN 8192
#define NBKT 256                              // value buckets over [0,1)
#define EPSF 1e-8f
#define LOG2E 1.4426950408889634f
#define LN2f 0.6931471805599453f
#define CHUNKS 4
#define CH (NN / CHUNKS)                      // 2048 j-elements per chunk
#define RG (NN / 16)                          // 512 row-groups
#define NBLK (RG * CHUNKS)                    // 2048 blocks in dispatch B
#define A2SCALE (20.0f * LOG2E)               // (pred/0.05)*log2(e)

__device__ __forceinline__ int bucket_of(float y) {
    return min(max((int)(y * 256.0f), 0), NBKT - 1);
}

// ---------------------------------------------------------------------------
// Dispatch A: single-block counting sort, 256 buckets, all-LDS hist/scan.
// Bucket separation >= 2 guarantees gap >= 1/256 - rounding >> EPS, so only
// the ~2-bucket straddle needs the exact compare in dispatch B.
// Within-bucket order arbitrary (loss is permutation-invariant there).
// ---------------------------------------------------------------------------
__global__ __launch_bounds__(1024) void sortk(const float* __restrict__ yt,
                                              const float* __restrict__ pred,
                                              float* __restrict__ ybkt,
                                              float* __restrict__ a2bkt,
                                              int* __restrict__ offs) {
    __shared__ int hist[NBKT];
    __shared__ int cur[NBKT];
    const int t = threadIdx.x;
    if (t < NBKT) hist[t] = 0;
    __syncthreads();

    float yv[8]; int bv[8];
#pragma unroll
    for (int k = 0; k < 8; ++k) {
        const int i = t + k * 1024;
        const float y = yt[i];
        const int b = bucket_of(y);
        yv[k] = y; bv[k] = b;
        atomicAdd(&hist[b], 1);
    }
    __syncthreads();

    if (t < 64) {                             // wave 0: scan 256 buckets, 4/lane
        int loc[4]; int sum = 0;
#pragma unroll
        for (int k = 0; k < 4; ++k) { loc[k] = hist[t * 4 + k]; sum += loc[k]; }
        int incl = sum;
        for (int d = 1; d < 64; d <<= 1) {
            int n = __shfl_up(incl, d);
            if (t >= d) incl += n;
        }
        int run = incl - sum;                 // exclusive base
#pragma unroll
        for (int k = 0; k < 4; ++k) {
            cur[t * 4 + k] = run;
            offs[t * 4 + k] = run;
            run += loc[k];
        }
        if (t == 63) offs[NBKT] = run;        // == NN
    }
    __syncthreads();

#pragma unroll
    for (int k = 0; k < 8; ++k) {
        const int i = t + k * 1024;
        const int pos = atomicAdd(&cur[bv[k]], 1);
        ybkt[pos] = yv[k];
        a2bkt[pos] = pred[i] * A2SCALE;
    }
}

// ---------------------------------------------------------------------------
// Dispatch B: LDS-staged sorted-prefix two-pass + embedded spin finalize.
// Block (rg,c): 16 sorted rows x chunk c. LDS holds (a_j, a_j*y_j) (16 KB).
// FIX vs r8: staging bound is BLOCK-uniform (from x15, the block's largest
// row) so every wave's read range is fully staged; r8 used per-wave bounds
// and wave 3 read unstaged LDS -> NaN.
// Unmasked prefix: L = fma(a,x,-c), 2 ops/pair. Straddle: exact compare with
// y read from global (L2-hit). Block 7 == (rg=511,c=3) under the swizzle:
// longest work; spins on all 2048 done-flags, then finalizes inline.
// Flags rely on harness 0xAA-poison of d_ws: 0xAAAAAAAA < 1 as int.
// ---------------------------------------------------------------------------
__global__ __launch_bounds__(256) void pro_fused(const float* __restrict__ ybkt,
                                                 const float* __restrict__ a2bkt,
                                                 const int* __restrict__ offs,
                                                 float2* __restrict__ partial,
                                                 int* __restrict__ pflag,
                                                 float* __restrict__ out) {
    __shared__ float4 ac_s[CH / 2];           // 16 KB: (a0, a0*y0, a1, a1*y1)
    __shared__ float fredm[4];
    __shared__ float2 fred2[4];

    const int t = threadIdx.x, lane = t & 63, wave = t >> 6;
    const int braw = blockIdx.x;
    const int rgl = braw >> 2, c = braw & 3;
    // load-balance swizzle: pair long (high rg) with short (low rg)
    const int rg = (rgl & 1) ? (RG - 1 - (rgl >> 1)) : (rgl >> 1);
    const int j0 = c * CH;
    const int row0 = rg * 16 + wave * 4;

    const float x15 = ybkt[rg * 16 + 15];
    const int e15 = offs[bucket_of(x15) + 1];          // block-uniform end bound
    const bool active = (e15 > j0);                    // block-uniform

    float M[4] = {-INFINITY, -INFINITY, -INFINITY, -INFINITY};
    float s[4] = {0.f, 0.f, 0.f, 0.f};

    if (active) {
        // ---- BLOCK-UNIFORM staging bound (covers every wave's range) ----
        const int stage_n = min(CH, (min(max(e15 - j0, 0), CH) + 127) & ~127);
        const float4* yb4 = (const float4*)(ybkt + j0);
        const float4* ab4 = (const float4*)(a2bkt + j0);
        for (int i = t; i < stage_n / 4; i += 256) {
            const float4 y4 = yb4[i];
            const float4 a4 = ab4[i];
            ac_s[2 * i]     = make_float4(a4.x, a4.x * y4.x, a4.y, a4.y * y4.y);
            ac_s[2 * i + 1] = make_float4(a4.z, a4.z * y4.z, a4.w, a4.w * y4.w);
        }
        __syncthreads();

        // ---- per-wave bounds ----
        float x[4];
#pragma unroll
        for (int r = 0; r < 4; ++r) x[r] = ybkt[row0 + r];
        const int b0 = bucket_of(x[0]), b3 = bucket_of(x[3]);
        const int u0 = (b0 > 0) ? offs[b0 - 1] : 0;   // below: valid for all 4 rows
        const int e3 = offs[b3 + 1];                  // at/after: invalid for all
        int lo = min(max(u0 - j0, 0), CH);
        const int nbi = lo >> 7;                      // full 128-elem unmasked iters
        lo = nbi << 7;
        const int hi = min(max(e3 - j0, lo), CH);     // hi <= stage_n by e3 <= e15

        // ---- pass 1: max of L = fma(a, x, -c) over the valid prefix ----
        for (int i = 0; i < nbi; ++i) {
            const float4 v = ac_s[i * 64 + lane];
#pragma unroll
            for (int r = 0; r < 4; ++r) {
                const float L0 = __builtin_fmaf(v.x, x[r], -v.y);
                const float L1 = __builtin_fmaf(v.z, x[r], -v.w);
                M[r] = fmaxf(M[r], fmaxf(L0, L1));
            }
        }
        for (int base = lo; base < hi; base += 128) {   // straddle: exact compare
            const float2 y2 = *(const float2*)(ybkt + j0 + base + 2 * lane);
            const float4 v = ac_s[(base >> 1) + lane];
#pragma unroll
            for (int r = 0; r < 4; ++r) {
                const float W0 = x[r] - y2.x, W1 = x[r] - y2.y;
                const float L0 = __builtin_fmaf(v.x, x[r], -v.y);
                const float L1 = __builtin_fmaf(v.z, x[r], -v.w);
                M[r] = fmaxf(M[r], fmaxf((W0 > EPSF) ? L0 : -INFINITY,
                                         (W1 > EPSF) ? L1 : -INFINITY));
            }
        }
#pragma unroll
        for (int r = 0; r < 4; ++r)
            for (int m = 1; m < 64; m <<= 1) M[r] = fmaxf(M[r], __shfl_xor(M[r], m));

        // ---- pass 2: sum exp2(L - M) over the same set ----
        for (int i = 0; i < nbi; ++i) {
            const float4 v = ac_s[i * 64 + lane];
#pragma unroll
            for (int r = 0; r < 4; ++r) {
                s[r] += exp2f(__builtin_fmaf(v.x, x[r], -v.y) - M[r]);
                s[r] += exp2f(__builtin_fmaf(v.z, x[r], -v.w) - M[r]);
            }
        }
        for (int base = lo; base < hi; base += 128) {
            const float2 y2 = *(const float2*)(ybkt + j0 + base + 2 * lane);
            const float4 v = ac_s[(base >> 1) + lane];
#pragma unroll
            for (int r = 0; r < 4; ++r) {
                const float W0 = x[r] - y2.x, W1 = x[r] - y2.y;
                const float t0 = __builtin_fmaf(v.x, x[r], -v.y) - M[r];
                const float t1 = __builtin_fmaf(v.z, x[r], -v.w) - M[r];
                s[r] += exp2f((W0 > EPSF) ? t0 : -INFINITY);
                s[r] += exp2f((W1 > EPSF) ? t1 : -INFINITY);
            }
        }
#pragma unroll
        for (int r = 0; r < 4; ++r)
            for (int m = 1; m < 64; m <<= 1) s[r] += __shfl_xor(s[r], m);
    }

    if (lane == 0) {
#pragma unroll
        for (int r = 0; r < 4; ++r)
            partial[c * NN + row0 + r] = make_float2(M[r], s[r]);
    }

    __syncthreads();
    if (t == 0) {
        __threadfence();
        __hip_atomic_store(&pflag[braw], 1, __ATOMIC_RELEASE, __HIP_MEMORY_SCOPE_AGENT);
    }

    // ---- embedded finalize: block 7 (rg=511, c=3 -> longest work) ----
    if (braw == 7) {
        for (int i = t; i < NBLK; i += 256) {
            while (__hip_atomic_load(&pflag[i], __ATOMIC_ACQUIRE, __HIP_MEMORY_SCOPE_AGENT) < 1) {
                __builtin_amdgcn_s_sleep(8);
            }
        }
        __syncthreads();
        __threadfence();

        float mn = INFINITY;
        for (int i = t; i < NN; i += 256) mn = fminf(mn, ybkt[i]);
#pragma unroll
        for (int m = 1; m < 64; m <<= 1) mn = fminf(mn, __shfl_xor(mn, m));
        if (lane == 0) fredm[wave] = mn;
        __syncthreads();
        const float ymin = fminf(fminf(fredm[0], fredm[1]), fminf(fredm[2], fredm[3]));

        float wtot = 0.f, wcnt = 0.f;
        for (int p = t; p < NN; p += 256) {
            const float xv = ybkt[p];
            const float w = xv - ymin;        // == weight_k (max masked gap)
            const float lp = a2bkt[p] * w;    // logit_pos, log2-scaled
            const float2 p0 = partial[0 * NN + p];
            const float2 p1 = partial[1 * NN + p];
            const float2 p2 = partial[2 * NN + p];
            const float2 p3 = partial[3 * NN + p];
            const float Mx = fmaxf(lp, fmaxf(fmaxf(p0.x, p1.x), fmaxf(p2.x, p3.x)));
            float sum = exp2f(lp - Mx);
            sum += p0.y * exp2f(p0.x - Mx);
            sum += p1.y * exp2f(p1.x - Mx);
            sum += p2.y * exp2f(p2.x - Mx);
            sum += p3.y * exp2f(p3.x - Mx);
            const float logp = (lp - Mx) * LN2f - __logf(sum);
            if (w > EPSF) { wtot += logp; wcnt += 1.f; }
        }
#pragma unroll
        for (int m = 1; m < 64; m <<= 1) { wtot += __shfl_xor(wtot, m); wcnt += __shfl_xor(wcnt, m); }
        if (lane == 0) fred2[wave] = make_float2(wtot, wcnt);
        __syncthreads();
        if (t == 0) {
            const float bt = fred2[0].x + fred2[1].x + fred2[2].x + fred2[3].x;
            const float bc = fred2[0].y + fred2[1].y + fred2[2].y + fred2[3].y;
            out[0] = (bc > 0.f) ? (-bt / bc) : 0.f;
        }
    }
}

extern "C" void kernel_launch(void* const* d_in, const int* in_sizes, int n_in,
                              void* d_out, int out_size, void* d_ws, size_t ws_size,
                              hipStream_t stream) {
    const float* pred = (const float*)d_in[0];  // predict_similarity
    const float* yt   = (const float*)d_in[1];  // true_similarity

    float* ybkt   = (float*)d_ws;               // [NN]
    float* a2bkt  = ybkt + NN;                  // [NN]
    int*   offs   = (int*)(a2bkt + NN);         // [NBKT+1] (+pad to even)
    int*   pflag  = offs + NBKT + 8;            // [NBLK]  (264+2048 ints -> partial 16B-aligned)
    float2* partial = (float2*)(pflag + NBLK);  // [CHUNKS][NN] — fully overwritten

    sortk<<<1, 1024, 0, stream>>>(yt, pred, ybkt, a2bkt, offs);
    pro_fused<<<NBLK, 256, 0, stream>>>(ybkt, a2bkt, offs, partial, pflag, (float*)d_out);
}